// Round 2
// baseline (184.380 us; speedup 1.0000x reference)
//
#include <hip/hip_runtime.h>

typedef int v4i __attribute__((ext_vector_type(4)));

#define B_DIM   16
#define IN_DIM  8192
#define OUT_DIM 28672
#define KH      64              // K-steps (K=64) per half: 8192 / 64 / 2

// pack low bytes of 4 int32 lanes -> one dword (3x v_perm_b32)
static __device__ __forceinline__ unsigned pack_lo_bytes(v4i q) {
  unsigned t0 = __builtin_amdgcn_perm((unsigned)q.y, (unsigned)q.x, 0x00000400u);
  unsigned t1 = __builtin_amdgcn_perm((unsigned)q.w, (unsigned)q.z, 0x00000400u);
  return __builtin_amdgcn_perm(t1, t0, 0x05040100u);
}

// ---- pre-pass: per-row 2-level int8 quantization of x, packed in MFMA A-fragment order ----
// k decomposition: kk = k>>6; within 64-chunk: d = (k>>4)&3 (dword slot), grp = (k>>2)&3
// (lane k-group), j = k&3 (byte in dword).
// byte for (b,k) lives at: kk*1024 + grp*256 + b*16 + d*4 + j
// GEMM lane l = grp*16+b reads 16B at kk*1024 + l*16; its dword d, byte j = k  kk*64+d*16+grp*4+j.
// B-side uses the identical (grp,d,j)->k map, so the MFMA k-slot permutation cancels exactly.
__global__ __launch_bounds__(256) void xquant_kernel(
    const float* __restrict__ x,
    unsigned char* __restrict__ q1p,
    unsigned char* __restrict__ q2p,
    float* __restrict__ scales)
{
  const int b   = blockIdx.x;    // 16 blocks, one per batch row
  const int tid = threadIdx.x;   // 256 threads, 32 consecutive k each
  const float* xr = x + (size_t)b * IN_DIM + tid * 32;

  float v[32];
  float m = 0.0f;
#pragma unroll
  for (int i = 0; i < 8; ++i) {
    float4 f = ((const float4*)xr)[i];
    v[i*4+0] = f.x; v[i*4+1] = f.y; v[i*4+2] = f.z; v[i*4+3] = f.w;
    m = fmaxf(m, fmaxf(fmaxf(fabsf(f.x), fabsf(f.y)), fmaxf(fabsf(f.z), fabsf(f.w))));
  }
#pragma unroll
  for (int off = 32; off >= 1; off >>= 1)
    m = fmaxf(m, __shfl_xor(m, off));
  __shared__ float lmax[4];
  if ((tid & 63) == 0) lmax[tid >> 6] = m;
  __syncthreads();
  m = fmaxf(fmaxf(lmax[0], lmax[1]), fmaxf(lmax[2], lmax[3]));
  m = fmaxf(m, 1e-20f);

  const float s1   = m * (1.0f / 127.0f);
  const float inv1 = 1.0f / s1;
  const float s2   = s1 * (1.0f / 254.0f);
  const float inv2 = 1.0f / s2;
  if (tid == 0) { scales[b] = s1; scales[16 + b] = s2; }

  // thread covers k = tid*32 + idx, idx = i16*16 + grp*4 + j; kk = tid>>1, h2 = tid&1
  // d = h2*2 + i16  ->  byte pos = kk*1024 + grp*256 + b*16 + h2*8 + i16*4 + j
  const int kk = tid >> 1, h2 = tid & 1;
  unsigned char* b1 = q1p + kk * 1024 + b * 16 + h2 * 8;
  unsigned char* b2 = q2p + kk * 1024 + b * 16 + h2 * 8;
#pragma unroll
  for (int i16 = 0; i16 < 2; ++i16) {
#pragma unroll
    for (int grp = 0; grp < 4; ++grp) {
      unsigned a1 = 0, a2 = 0;
#pragma unroll
      for (int j = 0; j < 4; ++j) {
        const float xv = v[i16*16 + grp*4 + j];
        float q1 = rintf(xv * inv1);
        q1 = fminf(127.0f, fmaxf(-127.0f, q1));
        const float r = fmaf(-s1, q1, xv);
        float q2 = rintf(r * inv2);
        q2 = fminf(127.0f, fmaxf(-127.0f, q2));
        a1 |= ((unsigned)((int)q1 & 0xff)) << (8*j);
        a2 |= ((unsigned)((int)q2 & 0xff)) << (8*j);
      }
      *(unsigned*)(b1 + grp*256 + i16*4) = a1;
      *(unsigned*)(b2 + grp*256 + i16*4) = a2;
    }
  }
}

// ---- main GEMM: 256 blocks x 14 waves; wave (g,h) = 16 output channels, K-half h ----
// Weight read per instruction: 16 rows x one fully-consumed 64B line (4 grp-lanes x 16B
// contiguous) -> minimal request count. Split-K partials are int32, combined exactly in LDS.
__global__ __launch_bounds__(896, 4) void qgemm_kernel(
    const int* __restrict__ w,              // int8 values stored as int32, [OUT_DIM][IN_DIM]
    const unsigned char* __restrict__ q1p,
    const unsigned char* __restrict__ q2p,
    const float* __restrict__ scales,       // s1[16], s2[16]
    const float* __restrict__ wscaler,      // [OUT_DIM]
    float* __restrict__ out)                // [16][OUT_DIM] f32
{
  const int lane = threadIdx.x & 63;
  const int wv   = threadIdx.x >> 6;        // 0..13
  const int g    = wv % 7;                  // row group
  const int h    = wv / 7;                  // k-half
  const int col  = lane & 15;
  const int grp  = lane >> 4;
  const int o    = blockIdx.x * 112 + g * 16 + col;

  // lane's weight bytes for step kk, piece p: wpb + kk*256 + p*64
  const char* wpb = (const char*)(w + (size_t)o * IN_DIM + h * (IN_DIM/2)) + grp * 16;
  const unsigned char* x1p = q1p + h * (KH*1024) + lane * 16;
  const unsigned char* x2p = q2p + h * (KH*1024) + lane * 16;

  v4i acc1 = {0,0,0,0}, acc2 = {0,0,0,0};

  v4i wb[2][4], xb1[2], xb2[2];
#pragma unroll
  for (int i = 0; i < 2; ++i) {
#pragma unroll
    for (int p = 0; p < 4; ++p)
      wb[i][p] = *(const v4i*)(wpb + i*256 + p*64);
    xb1[i] = *(const v4i*)(x1p + (size_t)i * 1024);
    xb2[i] = *(const v4i*)(x2p + (size_t)i * 1024);
  }

  for (int kk = 0; kk < KH; kk += 2) {
#pragma unroll
    for (int i = 0; i < 2; ++i) {
      int kn = kk + i + 2; if (kn > KH - 1) kn = KH - 1;
      v4i nw0 = *(const v4i*)(wpb + (size_t)kn*256 + 0);
      v4i nw1 = *(const v4i*)(wpb + (size_t)kn*256 + 64);
      v4i nw2 = *(const v4i*)(wpb + (size_t)kn*256 + 128);
      v4i nw3 = *(const v4i*)(wpb + (size_t)kn*256 + 192);
      v4i nx1 = *(const v4i*)(x1p + (size_t)kn * 1024);
      v4i nx2 = *(const v4i*)(x2p + (size_t)kn * 1024);

      v4i bw;
      bw.x = (int)pack_lo_bytes(wb[i][0]);
      bw.y = (int)pack_lo_bytes(wb[i][1]);
      bw.z = (int)pack_lo_bytes(wb[i][2]);
      bw.w = (int)pack_lo_bytes(wb[i][3]);
      acc1 = __builtin_amdgcn_mfma_i32_16x16x64_i8(xb1[i], bw, acc1, 0, 0, 0);
      acc2 = __builtin_amdgcn_mfma_i32_16x16x64_i8(xb2[i], bw, acc2, 0, 0, 0);

      wb[i][0] = nw0; wb[i][1] = nw1; wb[i][2] = nw2; wb[i][3] = nw3;
      xb1[i] = nx1; xb2[i] = nx2;
    }
  }

  // split-K combine: h=1 waves publish int32 partials, h=0 waves add (exact) and store.
  __shared__ v4i lds1[7][64], lds2[7][64];
  if (h == 1) { lds1[g][lane] = acc1; lds2[g][lane] = acc2; }
  __syncthreads();
  if (h == 0) {
    const v4i p1 = lds1[g][lane], p2 = lds2[g][lane];
    const float sc = wscaler[o];
#pragma unroll
    for (int r = 0; r < 4; ++r) {
      const int b = grp * 4 + r;          // C/D layout: row=(lane>>4)*4+reg, col=lane&15
      const float val = scales[b]      * (float)(acc1[r] + p1[r])
                      + scales[16 + b] * (float)(acc2[r] + p2[r]);
      out[(size_t)b * OUT_DIM + o] = val * sc;
    }
  }
}

extern "C" void kernel_launch(void* const* d_in, const int* in_sizes, int n_in,
                              void* d_out, int out_size, void* d_ws, size_t ws_size,
                              hipStream_t stream) {
  const float* x       = (const float*)d_in[0];
  const int*   w       = (const int*)d_in[1];     // int8 range, int32 storage
  const float* wscaler = (const float*)d_in[2];
  float* out = (float*)d_out;

  unsigned char* ws  = (unsigned char*)d_ws;
  unsigned char* q1p = ws;                        // 128 KiB
  unsigned char* q2p = ws + 131072;               // 128 KiB
  float* scales      = (float*)(ws + 262144);     // 32 floats

  xquant_kernel<<<16, 256, 0, stream>>>(x, q1p, q2p, scales);
  qgemm_kernel<<<256, 896, 0, stream>>>(w, q1p, q2p, scales, wscaler, out);
}

// Round 3
// 167.138 us; speedup vs baseline: 1.1032x; 1.1032x over previous
//
#include <hip/hip_runtime.h>

typedef int v4i __attribute__((ext_vector_type(4)));

#define B_DIM   16
#define IN_DIM  8192
#define OUT_DIM 28672
#define NKS     128             // k-steps of K=64 int8
#define NS      32              // super-steps (4 k-steps = 1KB/row each)

// pack low bytes of 4 int32 lanes -> one dword (3x v_perm_b32)
static __device__ __forceinline__ unsigned pack_lo_bytes(v4i q) {
  unsigned t0 = __builtin_amdgcn_perm((unsigned)q.y, (unsigned)q.x, 0x00000400u);
  unsigned t1 = __builtin_amdgcn_perm((unsigned)q.w, (unsigned)q.z, 0x00000400u);
  return __builtin_amdgcn_perm(t1, t0, 0x05040100u);
}

// ---- pre-pass: per-row 2-level int8 quantization of x, packed in MFMA A-fragment order ----
// (byte-identical layout to R2; k = kk*64 + d*16 + grp*4 + j lives at
//  kk*1024 + grp*256 + b*16 + d*4 + j. B-side uses the same map, permutation cancels.)
__global__ __launch_bounds__(256) void xquant_kernel(
    const float* __restrict__ x,
    unsigned char* __restrict__ q1p,
    unsigned char* __restrict__ q2p,
    float* __restrict__ scales)
{
  const int b   = blockIdx.x;
  const int tid = threadIdx.x;
  const float* xr = x + (size_t)b * IN_DIM + tid * 32;

  float v[32];
  float m = 0.0f;
#pragma unroll
  for (int i = 0; i < 8; ++i) {
    float4 f = ((const float4*)xr)[i];
    v[i*4+0] = f.x; v[i*4+1] = f.y; v[i*4+2] = f.z; v[i*4+3] = f.w;
    m = fmaxf(m, fmaxf(fmaxf(fabsf(f.x), fabsf(f.y)), fmaxf(fabsf(f.z), fabsf(f.w))));
  }
#pragma unroll
  for (int off = 32; off >= 1; off >>= 1)
    m = fmaxf(m, __shfl_xor(m, off));
  __shared__ float lmax[4];
  if ((tid & 63) == 0) lmax[tid >> 6] = m;
  __syncthreads();
  m = fmaxf(fmaxf(lmax[0], lmax[1]), fmaxf(lmax[2], lmax[3]));
  m = fmaxf(m, 1e-20f);

  const float s1   = m * (1.0f / 127.0f);
  const float inv1 = 1.0f / s1;
  const float s2   = s1 * (1.0f / 254.0f);
  const float inv2 = 1.0f / s2;
  if (tid == 0) { scales[b] = s1; scales[16 + b] = s2; }

  const int kk = tid >> 1, h2 = tid & 1;
  unsigned char* b1 = q1p + kk * 1024 + b * 16 + h2 * 8;
  unsigned char* b2 = q2p + kk * 1024 + b * 16 + h2 * 8;
#pragma unroll
  for (int i16 = 0; i16 < 2; ++i16) {
#pragma unroll
    for (int grp = 0; grp < 4; ++grp) {
      unsigned a1 = 0, a2 = 0;
#pragma unroll
      for (int j = 0; j < 4; ++j) {
        const float xv = v[i16*16 + grp*4 + j];
        float q1 = rintf(xv * inv1);
        q1 = fminf(127.0f, fmaxf(-127.0f, q1));
        const float r = fmaf(-s1, q1, xv);
        float q2 = rintf(r * inv2);
        q2 = fminf(127.0f, fmaxf(-127.0f, q2));
        a1 |= ((unsigned)((int)q1 & 0xff)) << (8*j);
        a2 |= ((unsigned)((int)q2 & 0xff)) << (8*j);
      }
      *(unsigned*)(b1 + grp*256 + i16*4) = a1;
      *(unsigned*)(b2 + grp*256 + i16*4) = a2;
    }
  }
}

// issue the 16 weight loads of one super-step: 1KB contiguous per row, ascending addresses
static __device__ __forceinline__ void issue_w(v4i (&dst)[16], const char* wpb, int s) {
  const char* bp = wpb + (size_t)s * 1024;
#pragma unroll
  for (int kk2 = 0; kk2 < 4; ++kk2)
#pragma unroll
    for (int p = 0; p < 4; ++p)
      dst[kk2*4 + p] = *(const v4i*)(bp + kk2*256 + p*64);
}

static __device__ __forceinline__ void compute_ss(
    const v4i (&src)[16], int s,
    const unsigned char* x1p, const unsigned char* x2p,
    v4i& acc1, v4i& acc2) {
#pragma unroll
  for (int kk2 = 0; kk2 < 4; ++kk2) {
    const int kk = s*4 + kk2;
    const v4i xa = *(const v4i*)(x1p + (size_t)kk * 1024);
    const v4i xb = *(const v4i*)(x2p + (size_t)kk * 1024);
    v4i bw;
    bw.x = (int)pack_lo_bytes(src[kk2*4 + 0]);
    bw.y = (int)pack_lo_bytes(src[kk2*4 + 1]);
    bw.z = (int)pack_lo_bytes(src[kk2*4 + 2]);
    bw.w = (int)pack_lo_bytes(src[kk2*4 + 3]);
    acc1 = __builtin_amdgcn_mfma_i32_16x16x64_i8(xa, bw, acc1, 0, 0, 0);
    acc2 = __builtin_amdgcn_mfma_i32_16x16x64_i8(xb, bw, acc2, 0, 0, 0);
  }
}

// ---- main GEMM: 256 blocks x 7 waves; wave = 16 output channels over full K ----
__global__ __launch_bounds__(448, 2) void qgemm_kernel(
    const int* __restrict__ w,
    const unsigned char* __restrict__ q1p,
    const unsigned char* __restrict__ q2p,
    const float* __restrict__ scales,
    const float* __restrict__ wscaler,
    float* __restrict__ out)
{
  const int lane = threadIdx.x & 63;
  const int wv   = threadIdx.x >> 6;        // 0..6
  const int col  = lane & 15;
  const int grp  = lane >> 4;
  const int o    = blockIdx.x * 112 + wv * 16 + col;

  const char* wpb = (const char*)(w + (size_t)o * IN_DIM) + grp * 16;
  const unsigned char* x1p = q1p + lane * 16;
  const unsigned char* x2p = q2p + lane * 16;

  v4i acc1 = {0,0,0,0}, acc2 = {0,0,0,0};
  v4i wa[16], wb2[16];

  issue_w(wa, wpb, 0);
  for (int s = 0; s < NS; s += 2) {
    issue_w(wb2, wpb, s + 1);
    compute_ss(wa,  s,     x1p, x2p, acc1, acc2);
    if (s + 2 < NS) issue_w(wa, wpb, s + 2);
    compute_ss(wb2, s + 1, x1p, x2p, acc1, acc2);
  }

  // epilogue: C/D layout col=lane&15, row=(lane>>4)*4+reg
  const float sc = wscaler[o];
#pragma unroll
  for (int r = 0; r < 4; ++r) {
    const int b = grp * 4 + r;
    const float val = scales[b] * (float)acc1[r] + scales[16 + b] * (float)acc2[r];
    out[(size_t)b * OUT_DIM + o] = val * sc;
  }
}

extern "C" void kernel_launch(void* const* d_in, const int* in_sizes, int n_in,
                              void* d_out, int out_size, void* d_ws, size_t ws_size,
                              hipStream_t stream) {
  const float* x       = (const float*)d_in[0];
  const int*   w       = (const int*)d_in[1];
  const float* wscaler = (const float*)d_in[2];
  float* out = (float*)d_out;

  unsigned char* ws  = (unsigned char*)d_ws;
  unsigned char* q1p = ws;                        // 128 KiB
  unsigned char* q2p = ws + 131072;               // 128 KiB
  float* scales      = (float*)(ws + 262144);     // 32 floats

  xquant_kernel<<<16, 256, 0, stream>>>(x, q1p, q2p, scales);
  qgemm_kernel<<<256, 448, 0, stream>>>(w, q1p, q2p, scales, wscaler, out);
}